// Round 10
// baseline (191.014 us; speedup 1.0000x reference)
//
#include <hip/hip_runtime.h>
#include <math.h>

#define NE 32
#define HID 2880
#define NSTEP 90          // 2880/32 k-steps total
#define TT 64             // tokens per block
#define THREADS 256       // 4 waves; wave wv owns tokens [t0+16*wv, +16)
#define WSB_BYTES (3 * NSTEP * 2 * 64 * 16)   // 552960 B packed W fragments

typedef short bf16x8 __attribute__((ext_vector_type(8)));
typedef float f32x4 __attribute__((ext_vector_type(4)));

union FragU { uint4 q; bf16x8 v; };

// global_load_lds: wave-uniform LDS dest + lane*16; per-lane global src.
#define GLL(gsrc, ldst)                                                        \
  __builtin_amdgcn_global_load_lds(                                            \
      (const __attribute__((address_space(1))) unsigned int*)(gsrc),           \
      (__attribute__((address_space(3))) unsigned int*)(ldst), 16, 0, 0)

// ---------- kernel 0: split W into 3 bf16 limbs packed as B-fragments,
//            and zero the per-token-group arrival counters ------------------
__global__ void __launch_bounds__(256) wsplit_kernel(
    const float* __restrict__ w, unsigned int* __restrict__ wsB,
    int* __restrict__ cnt, int ntg)
{
  const int gid = blockIdx.x * 256 + threadIdx.x;   // 0..11519
  if (gid < ntg) cnt[gid] = 0;

  const int s  = gid >> 7;
  const int tl = (gid >> 6) & 1;
  const int l  = gid & 63;

  const float* src = w + (size_t)(tl * 16 + (l & 15)) * HID + s * 32 + ((l >> 4) * 8);
  float4 xa = *(const float4*)src;
  float4 xb = *(const float4*)(src + 4);
  float x[8] = {xa.x, xa.y, xa.z, xa.w, xb.x, xb.y, xb.z, xb.w};

  unsigned int u0[8], u1[8], u2[8];
#pragma unroll
  for (int j = 0; j < 8; ++j) {
    unsigned int ux = __float_as_uint(x[j]);
    u0[j] = ux & 0xFFFF0000u;
    float r1 = x[j] - __uint_as_float(u0[j]);
    u1[j] = __float_as_uint(r1) & 0xFFFF0000u;
    float r2 = r1 - __uint_as_float(u1[j]);
    u2[j] = __float_as_uint(r2);
  }

  uint4* dst = (uint4*)wsB;
  uint4 d;
  d.x = __builtin_amdgcn_perm(u0[1], u0[0], 0x07060302u);
  d.y = __builtin_amdgcn_perm(u0[3], u0[2], 0x07060302u);
  d.z = __builtin_amdgcn_perm(u0[5], u0[4], 0x07060302u);
  d.w = __builtin_amdgcn_perm(u0[7], u0[6], 0x07060302u);
  dst[((0 * NSTEP + s) * 2 + tl) * 64 + l] = d;
  d.x = __builtin_amdgcn_perm(u1[1], u1[0], 0x07060302u);
  d.y = __builtin_amdgcn_perm(u1[3], u1[2], 0x07060302u);
  d.z = __builtin_amdgcn_perm(u1[5], u1[4], 0x07060302u);
  d.w = __builtin_amdgcn_perm(u1[7], u1[6], 0x07060302u);
  dst[((1 * NSTEP + s) * 2 + tl) * 64 + l] = d;
  d.x = __builtin_amdgcn_perm(u2[1], u2[0], 0x07060302u);
  d.y = __builtin_amdgcn_perm(u2[3], u2[2], 0x07060302u);
  d.z = __builtin_amdgcn_perm(u2[5], u2[4], 0x07060302u);
  d.w = __builtin_amdgcn_perm(u2[7], u2[6], 0x07060302u);
  dst[((2 * NSTEP + s) * 2 + tl) * 64 + l] = d;
}

// ---------- kernel 1: MFMA GEMM partials + fused last-arrival topk ---------
__global__ void __launch_bounds__(THREADS) router_mfma(
    const float* __restrict__ hs,         // [T][HID]
    const unsigned int* __restrict__ wsB, // packed W fragments
    float* __restrict__ wsp,              // [KQ][T][NE] fp32 partials
    int* __restrict__ cnt,                // [ntg] arrival counters
    const float* __restrict__ bias,
    float* __restrict__ out,              // [T][NE] scores, then [T][4] idx
    int T, int KQ, int ntg)
{
  __shared__ float smem[2][TT * 64];      // 32 KB double-buffered h chunk
  __shared__ int slast;

  const int tid = threadIdx.x;
  const int wv  = __builtin_amdgcn_readfirstlane(tid >> 6);
  const int l   = tid & 63;
  const int q   = l >> 4;
  const int r15 = l & 15;
  const int tg  = blockIdx.x % ntg;
  const int kq  = blockIdx.x / ntg;
  const int t0  = tg * TT;

  int nsteps, s0;
  if (KQ == 4) { nsteps = (kq == 0) ? 24 : 22; s0 = (kq == 0) ? 0 : (2 + 22 * kq); }
  else         { nsteps = (kq == 0) ? 46 : 44; s0 = (kq == 0) ? 0 : 46; }
  const int nchunk = nsteps >> 1;         // 2 k-steps (64 k) per chunk

  int goff[4];
#pragma unroll
  for (int i = 0; i < 4; ++i) {
    int f = tid + 256 * i;
    int row = f >> 4;
    int G = (f & 15) ^ (row & 15);
    goff[i] = row * HID + G * 4;
  }

  const int hrowb = (wv * 16 + r15) * 256;

  f32x4 acc0 = {0.f, 0.f, 0.f, 0.f};
  f32x4 acc1 = {0.f, 0.f, 0.f, 0.f};

  const float* hbase = hs + (size_t)t0 * HID + s0 * 32;

  // prologue: stage chunk 0 (4 GLL/thread outstanding)
#pragma unroll
  for (int i = 0; i < 4; ++i)
    GLL(hbase + goff[i], (char*)smem + (tid + 256 * i) * 16);

  const uint4* wb = (const uint4*)wsB;

#pragma clang loop unroll(disable)
  for (int c = 0; c < nchunk; ++c) {
    const int sg0 = s0 + c * 2;

    // ---- 12 W-fragment loads (before GLLs' consumers; stay in flight) ----
    FragU W000, W001, W010, W011, W020, W021;
    FragU W100, W101, W110, W111, W120, W121;
    W000.q = wb[((0 * NSTEP + sg0) * 2 + 0) * 64 + l];
    W001.q = wb[((0 * NSTEP + sg0) * 2 + 1) * 64 + l];
    W010.q = wb[((1 * NSTEP + sg0) * 2 + 0) * 64 + l];
    W011.q = wb[((1 * NSTEP + sg0) * 2 + 1) * 64 + l];
    W020.q = wb[((2 * NSTEP + sg0) * 2 + 0) * 64 + l];
    W021.q = wb[((2 * NSTEP + sg0) * 2 + 1) * 64 + l];
    W100.q = wb[((0 * NSTEP + sg0 + 1) * 2 + 0) * 64 + l];
    W101.q = wb[((0 * NSTEP + sg0 + 1) * 2 + 1) * 64 + l];
    W110.q = wb[((1 * NSTEP + sg0 + 1) * 2 + 0) * 64 + l];
    W111.q = wb[((1 * NSTEP + sg0 + 1) * 2 + 1) * 64 + l];
    W120.q = wb[((2 * NSTEP + sg0 + 1) * 2 + 0) * 64 + l];
    W121.q = wb[((2 * NSTEP + sg0 + 1) * 2 + 1) * 64 + l];

    // ---- issue next chunk's GLLs, then counted wait for CURRENT chunk ----
    // outstanding: GLL_c(4, oldest) + W(12) + GLL_{c+1}(4) = 20 -> vmcnt(16)
    // last iter:   GLL_c(4, oldest) + W(12)                = 16 -> vmcnt(12)
    if (c + 1 < nchunk) {
      const float* hn = hbase + (c + 1) * 64;
      char* bn = (char*)smem + ((c + 1) & 1) * 16384;
#pragma unroll
      for (int i = 0; i < 4; ++i)
        GLL(hn + goff[i], bn + (tid + 256 * i) * 16);
      asm volatile("s_waitcnt vmcnt(16)" ::: "memory");
    } else {
      asm volatile("s_waitcnt vmcnt(12)" ::: "memory");
    }
    __builtin_amdgcn_s_barrier();   // raw: no vmcnt(0) drain attached

    const char* cb = (const char*)smem + (c & 1) * 16384;

#pragma unroll
    for (int sl = 0; sl < 2; ++sl) {
      float4 h0 = *(const float4*)(cb + hrowb + (((sl * 8 + 2 * q + 0) ^ r15) << 4));
      float4 h1 = *(const float4*)(cb + hrowb + (((sl * 8 + 2 * q + 1) ^ r15) << 4));
      float x[8] = {h0.x, h0.y, h0.z, h0.w, h1.x, h1.y, h1.z, h1.w};

      unsigned int u0[8], u1[8], u2[8];
#pragma unroll
      for (int j = 0; j < 8; ++j) {
        unsigned int ux = __float_as_uint(x[j]);
        u0[j] = ux & 0xFFFF0000u;
        float r1 = x[j] - __uint_as_float(u0[j]);
        u1[j] = __float_as_uint(r1) & 0xFFFF0000u;
        float r2 = r1 - __uint_as_float(u1[j]);
        u2[j] = __float_as_uint(r2);
      }
      FragU A0, A1, A2;
      A0.q.x = __builtin_amdgcn_perm(u0[1], u0[0], 0x07060302u);
      A0.q.y = __builtin_amdgcn_perm(u0[3], u0[2], 0x07060302u);
      A0.q.z = __builtin_amdgcn_perm(u0[5], u0[4], 0x07060302u);
      A0.q.w = __builtin_amdgcn_perm(u0[7], u0[6], 0x07060302u);
      A1.q.x = __builtin_amdgcn_perm(u1[1], u1[0], 0x07060302u);
      A1.q.y = __builtin_amdgcn_perm(u1[3], u1[2], 0x07060302u);
      A1.q.z = __builtin_amdgcn_perm(u1[5], u1[4], 0x07060302u);
      A1.q.w = __builtin_amdgcn_perm(u1[7], u1[6], 0x07060302u);
      A2.q.x = __builtin_amdgcn_perm(u2[1], u2[0], 0x07060302u);
      A2.q.y = __builtin_amdgcn_perm(u2[3], u2[2], 0x07060302u);
      A2.q.z = __builtin_amdgcn_perm(u2[5], u2[4], 0x07060302u);
      A2.q.w = __builtin_amdgcn_perm(u2[7], u2[6], 0x07060302u);

      if (sl == 0) {
        acc0 = __builtin_amdgcn_mfma_f32_16x16x32_bf16(A0.v, W000.v, acc0, 0, 0, 0);
        acc0 = __builtin_amdgcn_mfma_f32_16x16x32_bf16(A0.v, W010.v, acc0, 0, 0, 0);
        acc0 = __builtin_amdgcn_mfma_f32_16x16x32_bf16(A1.v, W000.v, acc0, 0, 0, 0);
        acc0 = __builtin_amdgcn_mfma_f32_16x16x32_bf16(A1.v, W010.v, acc0, 0, 0, 0);
        acc0 = __builtin_amdgcn_mfma_f32_16x16x32_bf16(A0.v, W020.v, acc0, 0, 0, 0);
        acc0 = __builtin_amdgcn_mfma_f32_16x16x32_bf16(A2.v, W000.v, acc0, 0, 0, 0);
        acc1 = __builtin_amdgcn_mfma_f32_16x16x32_bf16(A0.v, W001.v, acc1, 0, 0, 0);
        acc1 = __builtin_amdgcn_mfma_f32_16x16x32_bf16(A0.v, W011.v, acc1, 0, 0, 0);
        acc1 = __builtin_amdgcn_mfma_f32_16x16x32_bf16(A1.v, W001.v, acc1, 0, 0, 0);
        acc1 = __builtin_amdgcn_mfma_f32_16x16x32_bf16(A1.v, W011.v, acc1, 0, 0, 0);
        acc1 = __builtin_amdgcn_mfma_f32_16x16x32_bf16(A0.v, W021.v, acc1, 0, 0, 0);
        acc1 = __builtin_amdgcn_mfma_f32_16x16x32_bf16(A2.v, W001.v, acc1, 0, 0, 0);
      } else {
        acc0 = __builtin_amdgcn_mfma_f32_16x16x32_bf16(A0.v, W100.v, acc0, 0, 0, 0);
        acc0 = __builtin_amdgcn_mfma_f32_16x16x32_bf16(A0.v, W110.v, acc0, 0, 0, 0);
        acc0 = __builtin_amdgcn_mfma_f32_16x16x32_bf16(A1.v, W100.v, acc0, 0, 0, 0);
        acc0 = __builtin_amdgcn_mfma_f32_16x16x32_bf16(A1.v, W110.v, acc0, 0, 0, 0);
        acc0 = __builtin_amdgcn_mfma_f32_16x16x32_bf16(A0.v, W120.v, acc0, 0, 0, 0);
        acc0 = __builtin_amdgcn_mfma_f32_16x16x32_bf16(A2.v, W100.v, acc0, 0, 0, 0);
        acc1 = __builtin_amdgcn_mfma_f32_16x16x32_bf16(A0.v, W101.v, acc1, 0, 0, 0);
        acc1 = __builtin_amdgcn_mfma_f32_16x16x32_bf16(A0.v, W111.v, acc1, 0, 0, 0);
        acc1 = __builtin_amdgcn_mfma_f32_16x16x32_bf16(A1.v, W101.v, acc1, 0, 0, 0);
        acc1 = __builtin_amdgcn_mfma_f32_16x16x32_bf16(A1.v, W111.v, acc1, 0, 0, 0);
        acc1 = __builtin_amdgcn_mfma_f32_16x16x32_bf16(A0.v, W121.v, acc1, 0, 0, 0);
        acc1 = __builtin_amdgcn_mfma_f32_16x16x32_bf16(A2.v, W101.v, acc1, 0, 0, 0);
      }
    }
    __builtin_amdgcn_s_barrier();   // readers done before next iter's GLLs land
  }

  // ---- write partials (D layout m89: lane l reg r -> D[(l>>4)*4+r][l&15]) --
  float* dst = wsp + ((size_t)kq * T + t0 + wv * 16) * NE;
#pragma unroll
  for (int r = 0; r < 4; ++r) {
    dst[(q * 4 + r) * NE + r15]      = acc0[r];
    dst[(q * 4 + r) * NE + 16 + r15] = acc1[r];
  }

  // ---- last-arrival fused reduce + topk for this token group --------------
  __threadfence();
  __syncthreads();
  if (tid == 0) {
    int old = atomicAdd(&cnt[tg], 1);
    slast = (old == KQ - 1) ? 1 : 0;
  }
  __syncthreads();
  if (slast) {
    __threadfence();
    if (tid < TT) {
      const int tok = t0 + tid;
      float lg[NE];
#pragma unroll
      for (int e = 0; e < NE; e += 4) {
        float4 bb = *(const float4*)(bias + e);
        lg[e] = bb.x; lg[e+1] = bb.y; lg[e+2] = bb.z; lg[e+3] = bb.w;
      }
      for (int qq = 0; qq < KQ; ++qq) {
        const volatile float* p = wsp + ((size_t)qq * T + tok) * NE;
#pragma unroll
        for (int e = 0; e < NE; ++e) lg[e] += p[e];
      }

      float tv[4]; int ti[4];
#pragma unroll
      for (int kk = 0; kk < 4; ++kk) {
        float m = -INFINITY; int mi = 0;
#pragma unroll
        for (int e = 0; e < NE; ++e) {
          bool gt = lg[e] > m;      // strict >: lowest index wins ties (jax)
          m  = gt ? lg[e] : m;
          mi = gt ? e : mi;
        }
        tv[kk] = m; ti[kk] = mi;
#pragma unroll
        for (int e = 0; e < NE; ++e)
          lg[e] = (e == mi) ? -INFINITY : lg[e];
      }

      float e1 = __expf(tv[1] - tv[0]);
      float e2 = __expf(tv[2] - tv[0]);
      float e3 = __expf(tv[3] - tv[0]);
      float inv = 1.0f / (1.0f + e1 + e2 + e3);
      float pr[4] = {inv, e1 * inv, e2 * inv, e3 * inv};

      float* orow = out + (size_t)tok * NE;
#pragma unroll
      for (int g = 0; g < 8; ++g) {
        float4 v;
        float* vp = (float*)&v;
#pragma unroll
        for (int cb2 = 0; cb2 < 4; ++cb2) {
          int e = g * 4 + cb2;
          float xx = 0.f;
          xx = (e == ti[0]) ? pr[0] : xx;
          xx = (e == ti[1]) ? pr[1] : xx;
          xx = (e == ti[2]) ? pr[2] : xx;
          xx = (e == ti[3]) ? pr[3] : xx;
          vp[cb2] = xx;
        }
        *(float4*)(orow + g * 4) = v;
      }
      float* oidx = out + (size_t)T * NE + (size_t)tok * 4;
      float4 iv;
      iv.x = (float)ti[0]; iv.y = (float)ti[1];
      iv.z = (float)ti[2]; iv.w = (float)ti[3];
      *(float4*)oidx = iv;
    }
  }
}

extern "C" void kernel_launch(void* const* d_in, const int* in_sizes, int n_in,
                              void* d_out, int out_size, void* d_ws, size_t ws_size,
                              hipStream_t stream) {
  const float* hs   = (const float*)d_in[0];
  const float* w    = (const float*)d_in[1];
  const float* bias = (const float*)d_in[2];
  float* out        = (float*)d_out;

  const int T   = in_sizes[0] / HID;    // 16384
  const int ntg = T / TT;               // 256

  const size_t per_kq = (size_t)T * NE * 4;
  const int KQ = (ws_size >= WSB_BYTES + 4 * per_kq + 4096) ? 4 : 2;

  unsigned int* wsB = (unsigned int*)d_ws;
  float* wsp        = (float*)((char*)d_ws + WSB_BYTES);
  int* cnt          = (int*)((char*)d_ws + WSB_BYTES + (size_t)KQ * per_kq);

  hipLaunchKernelGGL(wsplit_kernel, dim3(45), dim3(256), 0, stream,
                     w, wsB, cnt, ntg);
  hipLaunchKernelGGL(router_mfma, dim3(ntg * KQ), dim3(THREADS), 0, stream,
                     hs, wsB, wsp, cnt, bias, out, T, KQ, ntg);
}

// Round 11
// 57.303 us; speedup vs baseline: 3.3334x; 3.3334x over previous
//
#include <hip/hip_runtime.h>
#include <math.h>

#define NE 32
#define HID 2880
#define NSTEP 90          // 2880/32 k-steps total
#define TT 64             // tokens per block (4 waves x 16 tokens)
#define THREADS 256
#define WSB_BYTES (3 * NSTEP * 2 * 64 * 16)   // 552960 B packed W fragments

typedef short bf16x8 __attribute__((ext_vector_type(8)));
typedef float f32x4 __attribute__((ext_vector_type(4)));

union FragU { uint4 q; bf16x8 v; };

// ---------- kernel 0: split W into 3 bf16 limbs packed as B-fragments ------
// Fragment (p, s, t): lane l holds 8 bf16 = W_p[t*16 + (l&15)][s*32 + (l>>4)*8 + j]
__global__ void __launch_bounds__(256) wsplit_kernel(
    const float* __restrict__ w, unsigned int* __restrict__ wsB)
{
  const int gid = blockIdx.x * 256 + threadIdx.x;   // 0..11519
  const int s  = gid >> 7;
  const int tl = (gid >> 6) & 1;
  const int l  = gid & 63;

  const float* src = w + (size_t)(tl * 16 + (l & 15)) * HID + s * 32 + ((l >> 4) * 8);
  float4 xa = *(const float4*)src;
  float4 xb = *(const float4*)(src + 4);
  float x[8] = {xa.x, xa.y, xa.z, xa.w, xb.x, xb.y, xb.z, xb.w};

  unsigned int u0[8], u1[8], u2[8];
#pragma unroll
  for (int j = 0; j < 8; ++j) {
    unsigned int ux = __float_as_uint(x[j]);
    u0[j] = ux & 0xFFFF0000u;                       // limb0 (truncated bf16)
    float r1 = x[j] - __uint_as_float(u0[j]);       // exact
    u1[j] = __float_as_uint(r1) & 0xFFFF0000u;      // limb1
    float r2 = r1 - __uint_as_float(u1[j]);         // exact
    u2[j] = __float_as_uint(r2);                    // limb2 (trunc on pack)
  }

  uint4* dst = (uint4*)wsB;
  uint4 d;
  d.x = __builtin_amdgcn_perm(u0[1], u0[0], 0x07060302u);
  d.y = __builtin_amdgcn_perm(u0[3], u0[2], 0x07060302u);
  d.z = __builtin_amdgcn_perm(u0[5], u0[4], 0x07060302u);
  d.w = __builtin_amdgcn_perm(u0[7], u0[6], 0x07060302u);
  dst[((0 * NSTEP + s) * 2 + tl) * 64 + l] = d;
  d.x = __builtin_amdgcn_perm(u1[1], u1[0], 0x07060302u);
  d.y = __builtin_amdgcn_perm(u1[3], u1[2], 0x07060302u);
  d.z = __builtin_amdgcn_perm(u1[5], u1[4], 0x07060302u);
  d.w = __builtin_amdgcn_perm(u1[7], u1[6], 0x07060302u);
  dst[((1 * NSTEP + s) * 2 + tl) * 64 + l] = d;
  d.x = __builtin_amdgcn_perm(u2[1], u2[0], 0x07060302u);
  d.y = __builtin_amdgcn_perm(u2[3], u2[2], 0x07060302u);
  d.z = __builtin_amdgcn_perm(u2[5], u2[4], 0x07060302u);
  d.w = __builtin_amdgcn_perm(u2[7], u2[6], 0x07060302u);
  dst[((2 * NSTEP + s) * 2 + tl) * 64 + l] = d;
}

// ---------- kernel 1: MFMA GEMM partials — no LDS, no barriers -------------
// A-frag loads straight from global: lane l = row (l&15), k (l>>4)*8..+8.
// Wave covers 16 rows x 128B = full cache lines. Waves fully independent;
// compiler emits counted vmcnt and pipelines; 16 waves/CU TLP hides latency.
__global__ void __launch_bounds__(THREADS, 4) router_mfma(
    const float* __restrict__ hs,         // [T][HID]
    const unsigned int* __restrict__ wsB, // packed W fragments
    float* __restrict__ wsp,              // [KQ][T][NE] fp32 partials
    int T, int KQ, int ntg)
{
  const int tid = threadIdx.x;
  const int wv  = __builtin_amdgcn_readfirstlane(tid >> 6);
  const int l   = tid & 63;
  const int q   = l >> 4;
  const int r15 = l & 15;
  const int tg  = blockIdx.x % ntg;
  const int kq  = blockIdx.x / ntg;
  const int t0  = tg * TT;

  int nsteps, s0;
  if (KQ == 4) { nsteps = (kq == 0) ? 24 : 22; s0 = (kq == 0) ? 0 : (2 + 22 * kq); }
  else         { nsteps = (kq == 0) ? 46 : 44; s0 = (kq == 0) ? 0 : 46; }

  // per-lane h row pointer (A-fragment layout)
  const float* arow = hs + (size_t)(t0 + wv * 16 + r15) * HID + q * 8 + s0 * 32;
  const uint4* wb = (const uint4*)wsB + (size_t)s0 * 128 + l;   // (s*2+t)*64+l, p=0

  f32x4 acc0 = {0.f, 0.f, 0.f, 0.f};
  f32x4 acc1 = {0.f, 0.f, 0.f, 0.f};

#pragma clang loop unroll_count(2)
  for (int s = 0; s < nsteps; ++s) {
    // h: 8 fp32, 32B contiguous per lane
    float4 ha = *(const float4*)(arow + s * 32);
    float4 hb = *(const float4*)(arow + s * 32 + 4);

    // W fragments: 6 x 16B per lane, coalesced, L2-hot
    const uint4* wbs = wb + (size_t)s * 128;
    FragU W00, W01, W10, W11, W20, W21;
    W00.q = wbs[0];
    W01.q = wbs[64];
    W10.q = wbs[(size_t)NSTEP * 128];
    W11.q = wbs[(size_t)NSTEP * 128 + 64];
    W20.q = wbs[(size_t)NSTEP * 256];
    W21.q = wbs[(size_t)NSTEP * 256 + 64];

    float x[8] = {ha.x, ha.y, ha.z, ha.w, hb.x, hb.y, hb.z, hb.w};
    unsigned int u0[8], u1[8], u2[8];
#pragma unroll
    for (int j = 0; j < 8; ++j) {
      unsigned int ux = __float_as_uint(x[j]);
      u0[j] = ux & 0xFFFF0000u;
      float r1 = x[j] - __uint_as_float(u0[j]);
      u1[j] = __float_as_uint(r1) & 0xFFFF0000u;
      float r2 = r1 - __uint_as_float(u1[j]);
      u2[j] = __float_as_uint(r2);
    }
    FragU A0, A1, A2;
    A0.q.x = __builtin_amdgcn_perm(u0[1], u0[0], 0x07060302u);
    A0.q.y = __builtin_amdgcn_perm(u0[3], u0[2], 0x07060302u);
    A0.q.z = __builtin_amdgcn_perm(u0[5], u0[4], 0x07060302u);
    A0.q.w = __builtin_amdgcn_perm(u0[7], u0[6], 0x07060302u);
    A1.q.x = __builtin_amdgcn_perm(u1[1], u1[0], 0x07060302u);
    A1.q.y = __builtin_amdgcn_perm(u1[3], u1[2], 0x07060302u);
    A1.q.z = __builtin_amdgcn_perm(u1[5], u1[4], 0x07060302u);
    A1.q.w = __builtin_amdgcn_perm(u1[7], u1[6], 0x07060302u);
    A2.q.x = __builtin_amdgcn_perm(u2[1], u2[0], 0x07060302u);
    A2.q.y = __builtin_amdgcn_perm(u2[3], u2[2], 0x07060302u);
    A2.q.z = __builtin_amdgcn_perm(u2[5], u2[4], 0x07060302u);
    A2.q.w = __builtin_amdgcn_perm(u2[7], u2[6], 0x07060302u);

    // 6 limb-products per expert-tile into the same fp32 accumulator
    acc0 = __builtin_amdgcn_mfma_f32_16x16x32_bf16(A0.v, W00.v, acc0, 0, 0, 0);
    acc0 = __builtin_amdgcn_mfma_f32_16x16x32_bf16(A0.v, W10.v, acc0, 0, 0, 0);
    acc0 = __builtin_amdgcn_mfma_f32_16x16x32_bf16(A1.v, W00.v, acc0, 0, 0, 0);
    acc0 = __builtin_amdgcn_mfma_f32_16x16x32_bf16(A1.v, W10.v, acc0, 0, 0, 0);
    acc0 = __builtin_amdgcn_mfma_f32_16x16x32_bf16(A0.v, W20.v, acc0, 0, 0, 0);
    acc0 = __builtin_amdgcn_mfma_f32_16x16x32_bf16(A2.v, W00.v, acc0, 0, 0, 0);
    acc1 = __builtin_amdgcn_mfma_f32_16x16x32_bf16(A0.v, W01.v, acc1, 0, 0, 0);
    acc1 = __builtin_amdgcn_mfma_f32_16x16x32_bf16(A0.v, W11.v, acc1, 0, 0, 0);
    acc1 = __builtin_amdgcn_mfma_f32_16x16x32_bf16(A1.v, W01.v, acc1, 0, 0, 0);
    acc1 = __builtin_amdgcn_mfma_f32_16x16x32_bf16(A1.v, W11.v, acc1, 0, 0, 0);
    acc1 = __builtin_amdgcn_mfma_f32_16x16x32_bf16(A0.v, W21.v, acc1, 0, 0, 0);
    acc1 = __builtin_amdgcn_mfma_f32_16x16x32_bf16(A2.v, W01.v, acc1, 0, 0, 0);
  }

  // D layout (m89, verified): lane l reg r holds D[(l>>4)*4 + r][l&15]
  float* dst = wsp + ((size_t)kq * T + t0 + wv * 16) * NE;
#pragma unroll
  for (int r = 0; r < 4; ++r) {
    dst[(q * 4 + r) * NE + r15]      = acc0[r];
    dst[(q * 4 + r) * NE + 16 + r15] = acc1[r];
  }
}

// ---------- kernel 2: reduce partials + bias, top-4, softmax, scatter ------
__global__ void __launch_bounds__(256) router_topk(
    const float* __restrict__ wsp, const float* __restrict__ bias,
    float* __restrict__ out, int T, int KQ)
{
  const int tok = blockIdx.x * 256 + threadIdx.x;

  float lg[NE];
#pragma unroll
  for (int e = 0; e < NE; e += 4) {
    float4 bb = *(const float4*)(bias + e);
    lg[e] = bb.x; lg[e+1] = bb.y; lg[e+2] = bb.z; lg[e+3] = bb.w;
  }
  for (int qq = 0; qq < KQ; ++qq) {
    const float* p = wsp + ((size_t)qq * T + tok) * NE;
#pragma unroll
    for (int e = 0; e < NE; e += 4) {
      float4 v = *(const float4*)(p + e);
      lg[e] += v.x; lg[e+1] += v.y; lg[e+2] += v.z; lg[e+3] += v.w;
    }
  }

  float tv[4]; int ti[4];
#pragma unroll
  for (int kk = 0; kk < 4; ++kk) {
    float m = -INFINITY; int mi = 0;
#pragma unroll
    for (int e = 0; e < NE; ++e) {
      bool gt = lg[e] > m;          // strict >: lowest index wins ties (jax)
      m  = gt ? lg[e] : m;
      mi = gt ? e : mi;
    }
    tv[kk] = m; ti[kk] = mi;
#pragma unroll
    for (int e = 0; e < NE; ++e)
      lg[e] = (e == mi) ? -INFINITY : lg[e];
  }

  float e1 = __expf(tv[1] - tv[0]);
  float e2 = __expf(tv[2] - tv[0]);
  float e3 = __expf(tv[3] - tv[0]);
  float inv = 1.0f / (1.0f + e1 + e2 + e3);
  float pr[4] = {inv, e1 * inv, e2 * inv, e3 * inv};

  float* orow = out + (size_t)tok * NE;
#pragma unroll
  for (int g = 0; g < 8; ++g) {
    float4 v;
    float* vp = (float*)&v;
#pragma unroll
    for (int cb = 0; cb < 4; ++cb) {
      int e = g * 4 + cb;
      float xx = 0.f;
      xx = (e == ti[0]) ? pr[0] : xx;
      xx = (e == ti[1]) ? pr[1] : xx;
      xx = (e == ti[2]) ? pr[2] : xx;
      xx = (e == ti[3]) ? pr[3] : xx;
      vp[cb] = xx;
    }
    *(float4*)(orow + g * 4) = v;
  }
  float* oidx = out + (size_t)T * NE + (size_t)tok * 4;
  float4 iv;
  iv.x = (float)ti[0]; iv.y = (float)ti[1]; iv.z = (float)ti[2]; iv.w = (float)ti[3];
  *(float4*)oidx = iv;
}

extern "C" void kernel_launch(void* const* d_in, const int* in_sizes, int n_in,
                              void* d_out, int out_size, void* d_ws, size_t ws_size,
                              hipStream_t stream) {
  const float* hs   = (const float*)d_in[0];
  const float* w    = (const float*)d_in[1];
  const float* bias = (const float*)d_in[2];
  float* out        = (float*)d_out;

  unsigned int* wsB = (unsigned int*)d_ws;
  float* wsp        = (float*)((char*)d_ws + WSB_BYTES);

  const int T   = in_sizes[0] / HID;    // 16384
  const int ntg = T / TT;               // 256

  const size_t per_kq = (size_t)T * NE * 4;
  const int KQ = (ws_size >= WSB_BYTES + 4 * per_kq) ? 4 : 2;

  hipLaunchKernelGGL(wsplit_kernel, dim3(45), dim3(256), 0, stream, w, wsB);
  hipLaunchKernelGGL(router_mfma, dim3(ntg * KQ), dim3(THREADS), 0, stream,
                     hs, wsB, wsp, T, KQ, ntg);
  hipLaunchKernelGGL(router_topk, dim3(T / 256), dim3(256), 0, stream,
                     wsp, bias, out, T, KQ);
}